// Round 3
// baseline (47227.573 us; speedup 1.0000x reference)
//
#include <hip/hip_runtime.h>

#define BB    64
#define TDEC  128
#define TENC  256
#define DIN   256
#define DENC  512
#define HHH   512
#define NG    1536
#define KTOT  1280

// ws float offsets
#define OFF_CNT   0                       // 128*3*64 u32 = 24576
#define OFF_HDOT  24576                   // 128*64*4 f32 = 32768
#define OFF_U     57344                   // 1024
#define OFF_ECTX  58368                   // 64*256
#define OFF_HG    74752                   // 64*512
#define OFF_CTXG  107520                  // 64*512
#define OFF_RHG   140288                  // 64*512
#define OFF_WP    173056                  // pack: 4*3*128*1280
#define WP_ELEMS  (4*3*128*1280)          // 1,966,080

// ---------------- small helpers ----------------
__device__ __forceinline__ float wave_sum(float v) {
#pragma unroll
    for (int o = 32; o; o >>= 1) v += __shfl_down(v, o, 64);
    return v;
}
__device__ __forceinline__ float wave_max(float v) {
#pragma unroll
    for (int o = 32; o; o >>= 1) v = fmaxf(v, __shfl_down(v, o, 64));
    return v;
}
__device__ __forceinline__ float ldA(float* p) {
    return __hip_atomic_load(p, __ATOMIC_RELAXED, __HIP_MEMORY_SCOPE_AGENT);
}
__device__ __forceinline__ void stA(float* p, float v) {
    __hip_atomic_store(p, v, __ATOMIC_RELAXED, __HIP_MEMORY_SCOPE_AGENT);
}
__device__ __forceinline__ void arrive(unsigned* c) {
    asm volatile("s_waitcnt vmcnt(0)" ::: "memory");
    __hip_atomic_fetch_add(c, 1u, __ATOMIC_RELAXED, __HIP_MEMORY_SCOPE_AGENT);
}
__device__ __forceinline__ void wait4(unsigned* c) {
    while (__hip_atomic_load(c, __ATOMIC_RELAXED, __HIP_MEMORY_SCOPE_AGENT) < 4u)
        __builtin_amdgcn_s_sleep(2);
}
__device__ __forceinline__ float blo(unsigned u) { return __uint_as_float(u << 16); }
__device__ __forceinline__ float bhi(unsigned u) { return __uint_as_float(u & 0xffff0000u); }
__device__ __forceinline__ unsigned short f2bf(float f) {
    unsigned u = __float_as_uint(f);
    u += 0x7fffu + ((u >> 16) & 1u);
    return (unsigned short)(u >> 16);
}

__device__ __forceinline__ float dot4f(const float* p, const float4& a) {
    float4 v = *(const float4*)p;
    return a.x*v.x + a.y*v.y + a.z*v.z + a.w*v.w;
}
__device__ __forceinline__ float dot8f(const float* p, const float* a) {
    float4 v0 = *(const float4*)p, v1 = *(const float4*)(p + 4);
    return a[0]*v0.x + a[1]*v0.y + a[2]*v0.z + a[3]*v0.w
         + a[4]*v1.x + a[5]*v1.y + a[6]*v1.z + a[7]*v1.w;
}
__device__ __forceinline__ float dot4b(const unsigned short* p, const float4& a) {
    uint2 u = *(const uint2*)p;
    return a.x*blo(u.x) + a.y*bhi(u.x) + a.z*blo(u.y) + a.w*bhi(u.y);
}
__device__ __forceinline__ float dot8b(const unsigned short* p, const float* a) {
    uint4 u = *(const uint4*)p;
    return a[0]*blo(u.x) + a[1]*bhi(u.x) + a[2]*blo(u.y) + a[3]*bhi(u.y)
         + a[4]*blo(u.z) + a[5]*bhi(u.z) + a[6]*blo(u.w) + a[7]*bhi(u.w);
}

// ---------------- precompute kernels ----------------
__global__ void k_u(const float* __restrict__ w1, const float* __restrict__ w2,
                    float* __restrict__ u) {
    int e = blockIdx.x;
    int lane = threadIdx.x;
    float p = 0.f;
#pragma unroll
    for (int k = lane; k < DENC; k += 64) p += w1[e*DENC + k] * w2[k];
    p = wave_sum(p);
    if (lane == 0) u[e] = p;
}

__global__ void k_ectx(const float* __restrict__ C, const float* __restrict__ u,
                       float* __restrict__ ectx) {
    int r = blockIdx.x*4 + (threadIdx.x >> 6);
    int lane = threadIdx.x & 63;
    const float* row = C + (size_t)r*DENC;
    const float* vc  = u + HHH;
    float p = 0.f;
#pragma unroll
    for (int k = 0; k < DENC/64; ++k) p += row[lane + k*64] * vc[lane + k*64];
    p = wave_sum(p);
    if (lane == 0) ectx[r] = p;
}

// pack: wp[((js*3+g)*128 + jp)*1280 + k] = (k<768 ? Wx[k][col] : Wh[k-768][col]), col=g*512+js*128+jp
template<bool BF>
__global__ void k_wpack(const float* __restrict__ Wx, const float* __restrict__ Wh,
                        void* __restrict__ wp) {
    int id = blockIdx.x*256 + threadIdx.x;
    int k = id % 1280;
    int rest = id / 1280;
    int jp = rest & 127;
    rest >>= 7;
    int g  = rest % 3;
    int js = rest / 3;
    int col = g*512 + js*128 + jp;
    float v = (k < 768) ? Wx[(size_t)k*NG + col] : Wh[(size_t)(k-768)*NG + col];
    if (BF) ((unsigned short*)wp)[id] = f2bf(v);
    else    ((float*)wp)[id] = v;
}

// ---------------- main kernel ----------------
// 256 blocks: b = blk>>2, js = blk&3. Block computes hidden slice [js*128, js*128+128) of batch b.
template<bool BF>
__launch_bounds__(256, 1)
__global__ void decoder(const float* __restrict__ inp, const float* __restrict__ C,
                        const float* __restrict__ bias, const void* __restrict__ wpv,
                        float* __restrict__ out, float* __restrict__ ws) {
    unsigned* cnt  = (unsigned*)ws;
    float* hdotP = ws + OFF_HDOT;
    float* u     = ws + OFF_U;
    float* ectx  = ws + OFF_ECTX;
    float* hG    = ws + OFF_HG;
    float* ctxG  = ws + OFF_CTXG;
    float* rhG   = ws + OFF_RHG;

    const int tid = threadIdx.x;
    const int l   = tid & 63;
    const int w   = tid >> 6;
    const int b   = blockIdx.x >> 2;
    const int js  = blockIdx.x & 3;

    __shared__ float sh_h[HHH];
    __shared__ float sh_c[HHH];
    __shared__ float sh_rh[HHH];
    __shared__ float sh_att[TENC];
    __shared__ float sh_red[4];
    __shared__ float sh_cred[2][128];
    __shared__ float sh_zr[2][128];
    __shared__ float sh_xh[128];
    __shared__ float sh_hh[128];
    __shared__ float sh_z[128];
    __shared__ float sh_u[128];
    __shared__ float sh_scal;

    const float* WF = (const float*)wpv + (size_t)js*3*128*1280;
    const unsigned short* WB = (const unsigned short*)wpv + (size_t)js*3*128*1280;

    if (tid < 128) sh_u[tid] = u[js*128 + tid];

    float ac[8], ah[8], ar[8];

    for (int t = 0; t < TDEC; ++t) {
        float accZ[32], accR[32], accH[32];

        // ===== phase X: x-part dots (independent of h / ctx) =====
        const float4 ax4 = *(const float4*)(inp + (size_t)(b*TDEC + t)*DIN + l*4);
#pragma unroll
        for (int q = 0; q < 32; ++q) {
            const int jq = w*32 + q;
            if (BF) {
                accZ[q] = dot4b(WB + (size_t)(0*128+jq)*1280 + l*4, ax4);
                accR[q] = dot4b(WB + (size_t)(1*128+jq)*1280 + l*4, ax4);
                accH[q] = dot4b(WB + (size_t)(2*128+jq)*1280 + l*4, ax4);
            } else {
                accZ[q] = dot4f(WF + (size_t)(0*128+jq)*1280 + l*4, ax4);
                accR[q] = dot4f(WF + (size_t)(1*128+jq)*1280 + l*4, ax4);
                accH[q] = dot4f(WF + (size_t)(2*128+jq)*1280 + l*4, ax4);
            }
        }

        // ===== waitC(t-1): stage h_prev, get hdot =====
        if (t > 0) {
            if (tid == 0) {
                wait4(&cnt[((t-1)*3 + 2)*64 + b]);
                float s0 = ldA(&hdotP[(t-1)*256 + b*4 + 0]);
                float s1 = ldA(&hdotP[(t-1)*256 + b*4 + 1]);
                float s2 = ldA(&hdotP[(t-1)*256 + b*4 + 2]);
                float s3 = ldA(&hdotP[(t-1)*256 + b*4 + 3]);
                sh_scal = (s0 + s1) + (s2 + s3);
            }
            __syncthreads();
            sh_h[tid]       = ldA(&hG[b*HHH + tid]);
            sh_h[tid + 256] = ldA(&hG[b*HHH + 256 + tid]);
        } else {
            if (tid == 0) sh_scal = 0.f;
            sh_h[tid] = 0.f; sh_h[tid + 256] = 0.f;
        }
        __syncthreads();
        const float hd = sh_scal;

        // ===== attention softmax (local to b) =====
        float e = fmaxf(hd + ectx[b*TENC + tid], 0.f);
        float wm = wave_max(e);
        if (l == 0) sh_red[w] = wm;
        __syncthreads();
        float mx = fmaxf(fmaxf(sh_red[0], sh_red[1]), fmaxf(sh_red[2], sh_red[3]));
        float ex = __expf(e - mx);
        float wse = wave_sum(ex);
        __syncthreads();
        if (l == 0) sh_red[w] = wse;
        __syncthreads();
        float dn = sh_red[0] + sh_red[1] + sh_red[2] + sh_red[3];
        sh_att[tid] = ex / dn;
        __syncthreads();

        // ===== ctx slice: ctx[js*128 + d'] = sum_t att[t] * C[b,t,:] =====
        {
            const int dp = tid & 127, hf = tid >> 7;
            const float* Cb = C + ((size_t)b*TENC + hf*128)*DENC + js*128 + dp;
            float acc = 0.f;
#pragma unroll 8
            for (int q = 0; q < 128; ++q) acc += sh_att[hf*128 + q] * Cb[(size_t)q*DENC];
            sh_cred[hf][dp] = acc;
        }
        __syncthreads();
        if (tid < 128) stA(&ctxG[b*HHH + js*128 + tid], sh_cred[0][tid] + sh_cred[1][tid]);
        __syncthreads();
        if (tid == 0) arrive(&cnt[(t*3 + 0)*64 + b]);   // event A: ctx slice ready

        // ===== h-part dots (only need h_prev) =====
#pragma unroll
        for (int e2 = 0; e2 < 8; ++e2) ah[e2] = sh_h[l*8 + e2];
#pragma unroll
        for (int q = 0; q < 32; ++q) {
            const int jq = w*32 + q;
            if (BF) {
                accZ[q] += dot8b(WB + (size_t)(0*128+jq)*1280 + 768 + l*8, ah);
                accR[q] += dot8b(WB + (size_t)(1*128+jq)*1280 + 768 + l*8, ah);
            } else {
                accZ[q] += dot8f(WF + (size_t)(0*128+jq)*1280 + 768 + l*8, ah);
                accR[q] += dot8f(WF + (size_t)(1*128+jq)*1280 + 768 + l*8, ah);
            }
        }

        // ===== waitA: stage full ctx, c-part dots =====
        if (tid == 0) wait4(&cnt[(t*3 + 0)*64 + b]);
        __syncthreads();
        sh_c[tid]       = ldA(&ctxG[b*HHH + tid]);
        sh_c[tid + 256] = ldA(&ctxG[b*HHH + 256 + tid]);
        __syncthreads();
#pragma unroll
        for (int e2 = 0; e2 < 8; ++e2) ac[e2] = sh_c[l*8 + e2];
#pragma unroll
        for (int q = 0; q < 32; ++q) {
            const int jq = w*32 + q;
            if (BF) {
                accZ[q] += dot8b(WB + (size_t)(0*128+jq)*1280 + 256 + l*8, ac);
                accR[q] += dot8b(WB + (size_t)(1*128+jq)*1280 + 256 + l*8, ac);
                accH[q] += dot8b(WB + (size_t)(2*128+jq)*1280 + 256 + l*8, ac);
            } else {
                accZ[q] += dot8f(WF + (size_t)(0*128+jq)*1280 + 256 + l*8, ac);
                accR[q] += dot8f(WF + (size_t)(1*128+jq)*1280 + 256 + l*8, ac);
                accH[q] += dot8f(WF + (size_t)(2*128+jq)*1280 + 256 + l*8, ac);
            }
        }

        // reduce z, r, xh
#pragma unroll
        for (int q = 0; q < 32; ++q) {
            float sz = wave_sum(accZ[q]);
            float sr = wave_sum(accR[q]);
            float sx = wave_sum(accH[q]);
            if (l == 0) { sh_zr[0][w*32+q] = sz; sh_zr[1][w*32+q] = sr; sh_xh[w*32+q] = sx; }
        }
        __syncthreads();

        // gates z, r ; publish rh = r * h_prev
        if (tid < 128) {
            const int j = js*128 + tid;
            float z = 1.f / (1.f + __expf(-(sh_zr[0][tid] + bias[j])));
            float r = 1.f / (1.f + __expf(-(sh_zr[1][tid] + bias[HHH + j])));
            sh_z[tid] = z;
            stA(&rhG[b*HHH + j], r * sh_h[j]);
        }
        __syncthreads();
        if (tid == 0) arrive(&cnt[(t*3 + 1)*64 + b]);   // event B: rh slice ready

        // ===== waitB: stage rh, hh dots =====
        if (tid == 0) wait4(&cnt[(t*3 + 1)*64 + b]);
        __syncthreads();
        sh_rh[tid]       = ldA(&rhG[b*HHH + tid]);
        sh_rh[tid + 256] = ldA(&rhG[b*HHH + 256 + tid]);
        __syncthreads();
#pragma unroll
        for (int e2 = 0; e2 < 8; ++e2) ar[e2] = sh_rh[l*8 + e2];
#pragma unroll
        for (int q = 0; q < 32; ++q) {
            const int jq = w*32 + q;
            float a2;
            if (BF) a2 = dot8b(WB + (size_t)(2*128+jq)*1280 + 768 + l*8, ar);
            else    a2 = dot8f(WF + (size_t)(2*128+jq)*1280 + 768 + l*8, ar);
            float s = wave_sum(a2);
            if (l == 0) sh_hh[w*32+q] = s;
        }
        __syncthreads();

        // ===== finish: h_new, output, hdot partial =====
        if (tid < 128) {
            const int j = js*128 + tid;
            float hhv = tanhf(sh_xh[tid] + bias[2*HHH + j] + sh_hh[tid]);
            float z = sh_z[tid];
            float hp = sh_h[j];
            float hn = z*hp + (1.f - z)*hhv;
            stA(&hG[b*HHH + j], hn);
            out[(size_t)(b*TDEC + t)*HHH + j] = hn;
            float p = sh_u[tid] * hn;
            float s = wave_sum(p);
            if (l == 0) sh_red[w] = s;
        }
        __syncthreads();
        if (tid == 0) {
            stA(&hdotP[t*256 + b*4 + js], sh_red[0] + sh_red[1]);
            arrive(&cnt[(t*3 + 2)*64 + b]);              // event C: h slice + hdot ready
        }
        __syncthreads();
    }
}

extern "C" void kernel_launch(void* const* d_in, const int* in_sizes, int n_in,
                              void* d_out, int out_size, void* d_ws, size_t ws_size,
                              hipStream_t stream) {
    const float* inputs = (const float*)d_in[0];
    const float* C      = (const float*)d_in[1];
    const float* w1     = (const float*)d_in[2];
    const float* w2     = (const float*)d_in[3];
    const float* Wx     = (const float*)d_in[4];
    const float* Wh     = (const float*)d_in[5];
    const float* bias   = (const float*)d_in[6];
    float* out = (float*)d_out;
    float* ws  = (float*)d_ws;

    // zero event counters (per-t, so one memset per launch suffices)
    hipMemsetAsync(ws, 0, 128*3*64*sizeof(unsigned), stream);

    k_u   <<<1024, 64,  0, stream>>>(w1, w2, ws + OFF_U);
    k_ectx<<<(BB*TENC)/4, 256, 0, stream>>>(C, ws + OFF_U, ws + OFF_ECTX);

    const size_t need_f32 = (size_t)(OFF_WP + WP_ELEMS) * 4u;
    void* wp = (void*)(ws + OFF_WP);
    if (ws_size >= need_f32) {
        k_wpack<false><<<WP_ELEMS/256, 256, 0, stream>>>(Wx, Wh, wp);
        decoder<false><<<256, 256, 0, stream>>>(inputs, C, bias, wp, out, ws);
    } else {
        k_wpack<true><<<WP_ELEMS/256, 256, 0, stream>>>(Wx, Wh, wp);
        decoder<true><<<256, 256, 0, stream>>>(inputs, C, bias, wp, out, ws);
    }
}

// Round 4
// 4687.625 us; speedup vs baseline: 10.0749x; 10.0749x over previous
//
#include <hip/hip_runtime.h>

#define BB    64
#define TDEC  128
#define TENC  256
#define DIN   256
#define DENC  512
#define HHH   512
#define NG    1536
#define KTOT  1280
#define NK4   320          // KTOT/4
#define NCOL  384          // 3 gates * 128 cols per js slice

// ws float offsets
#define OFF_CNT   0                       // 128*3*64 u32 = 24576
#define OFF_HDOT  24576                   // 128*64*4 f32 = 32768
#define OFF_U     57344                   // 1024
#define OFF_ECTX  58368                   // 64*256 = 16384
#define OFF_HG    74752                   // 64*512
#define OFF_CTXG  107520                  // 64*512
#define OFF_RHG   140288                  // 64*512
#define OFF_WP    173056                  // pack: 4*320*384*4k = 1,966,080 elems
#define WP_ELEMS  (4*NK4*NCOL*4)

// ---------------- small helpers ----------------
__device__ __forceinline__ float wave_sum(float v) {
#pragma unroll
    for (int o = 32; o; o >>= 1) v += __shfl_down(v, o, 64);
    return v;
}
__device__ __forceinline__ float wave_max(float v) {
#pragma unroll
    for (int o = 32; o; o >>= 1) v = fmaxf(v, __shfl_down(v, o, 64));
    return v;
}
__device__ __forceinline__ float ldA(float* p) {
    return __hip_atomic_load(p, __ATOMIC_RELAXED, __HIP_MEMORY_SCOPE_AGENT);
}
__device__ __forceinline__ void stA(float* p, float v) {
    __hip_atomic_store(p, v, __ATOMIC_RELAXED, __HIP_MEMORY_SCOPE_AGENT);
}
__device__ __forceinline__ void arrive(unsigned* c) {
    asm volatile("s_waitcnt vmcnt(0)" ::: "memory");
    __hip_atomic_fetch_add(c, 1u, __ATOMIC_RELAXED, __HIP_MEMORY_SCOPE_AGENT);
}
__device__ __forceinline__ void wait4(unsigned* c) {
    while (__hip_atomic_load(c, __ATOMIC_RELAXED, __HIP_MEMORY_SCOPE_AGENT) < 4u)
        __builtin_amdgcn_s_sleep(2);
}
__device__ __forceinline__ float blo(unsigned u) { return __uint_as_float(u << 16); }
__device__ __forceinline__ float bhi(unsigned u) { return __uint_as_float(u & 0xffff0000u); }
__device__ __forceinline__ unsigned short f2bf(float f) {
    unsigned u = __float_as_uint(f);
    u += 0x7fffu + ((u >> 16) & 1u);
    return (unsigned short)(u >> 16);
}

// one thread's partial dot over k4 in [k4lo,k4hi), weight element (k4, c),
// activations a4[k4 - aoff] (LDS float4 broadcast)
template<bool BF>
__device__ __forceinline__ float dotrange(const void* wp, size_t base, int c,
                                          int k4lo, int k4hi, const float4* a4,
                                          int aoff, float acc) {
    if (BF) {
        const uint2* w = (const uint2*)wp + base + c;
#pragma unroll 8
        for (int k4 = k4lo; k4 < k4hi; ++k4) {
            uint2 uu = w[(size_t)k4 * NCOL];
            float4 a = a4[k4 - aoff];
            acc = fmaf(blo(uu.x), a.x, acc);
            acc = fmaf(bhi(uu.x), a.y, acc);
            acc = fmaf(blo(uu.y), a.z, acc);
            acc = fmaf(bhi(uu.y), a.w, acc);
        }
    } else {
        const float4* w = (const float4*)wp + base + c;
#pragma unroll 8
        for (int k4 = k4lo; k4 < k4hi; ++k4) {
            float4 wv = w[(size_t)k4 * NCOL];
            float4 a = a4[k4 - aoff];
            acc = fmaf(wv.x, a.x, acc);
            acc = fmaf(wv.y, a.y, acc);
            acc = fmaf(wv.z, a.z, acc);
            acc = fmaf(wv.w, a.w, acc);
        }
    }
    return acc;
}

// ---------------- precompute kernels ----------------
__global__ void k_u(const float* __restrict__ w1, const float* __restrict__ w2,
                    float* __restrict__ u) {
    int e = blockIdx.x;
    int lane = threadIdx.x;
    float p = 0.f;
#pragma unroll
    for (int k = lane; k < DENC; k += 64) p += w1[e*DENC + k] * w2[k];
    p = wave_sum(p);
    if (lane == 0) u[e] = p;
}

__global__ void k_ectx(const float* __restrict__ C, const float* __restrict__ u,
                       float* __restrict__ ectx) {
    int r = blockIdx.x*4 + (threadIdx.x >> 6);
    int lane = threadIdx.x & 63;
    const float* row = C + (size_t)r*DENC;
    const float* vc  = u + HHH;
    float p = 0.f;
#pragma unroll
    for (int k = 0; k < DENC/64; ++k) p += row[lane + k*64] * vc[lane + k*64];
    p = wave_sum(p);
    if (lane == 0) ectx[r] = p;
}

// K-major pack: layout [js][k4][c][e], k=k4*4+e, col = (c>>7)*512 + js*128 + (c&127)
// source: k<768 -> Wx[k][col] ; k>=768 -> Wh[k-768][col]
template<bool BF>
__global__ void k_wpack(const float* __restrict__ Wx, const float* __restrict__ Wh,
                        void* __restrict__ wp) {
    int id = blockIdx.x*256 + threadIdx.x;      // < WP_ELEMS
    int e = id & 3;
    int q = id >> 2;
    int c = q % NCOL;
    q /= NCOL;
    int k4 = q % NK4;
    int js = q / NK4;
    int k = k4*4 + e;
    int col = (c >> 7)*512 + js*128 + (c & 127);
    float v = (k < 768) ? Wx[(size_t)k*NG + col] : Wh[(size_t)(k-768)*NG + col];
    if (BF) ((unsigned short*)wp)[id] = f2bf(v);
    else    ((float*)wp)[id] = v;
}

// ---------------- main kernel ----------------
// 256 blocks: b = blk>>2, js = blk&3. Thread c: gate = c>>7 (0=z,1=r,2=h), jp = c&127.
template<bool BF>
__launch_bounds__(384, 1)
__global__ void decoder(const float* __restrict__ inp, const float* __restrict__ C,
                        const float* __restrict__ bias, const void* __restrict__ wpv,
                        const float* __restrict__ u, float* __restrict__ ectx_g,
                        float* __restrict__ out, float* __restrict__ ws) {
    unsigned* cnt = (unsigned*)ws;
    float* hdotP = ws + OFF_HDOT;
    float* hG    = ws + OFF_HG;
    float* ctxG  = ws + OFF_CTXG;
    float* rhG   = ws + OFF_RHG;

    const int tid = threadIdx.x;
    const int w   = tid >> 6;
    const int b   = blockIdx.x >> 2;
    const int js  = blockIdx.x & 3;
    const int c    = tid;
    const int gate = c >> 7;
    const int jp   = c & 127;

    __shared__ __align__(16) float sh_kx[KTOT];   // [0,256)=x  [256,768)=ctx  [768,1280)=h_prev
    __shared__ __align__(16) float sh_rh[HHH];
    __shared__ float sh_att[TENC];
    __shared__ float sh_ectx[TENC];
    __shared__ float sh_u[128];
    __shared__ float sh_z[128];
    __shared__ float sh_cred[2][128];
    __shared__ float sh_red[8];
    __shared__ float sh_scal;

    const float4* kx4 = (const float4*)sh_kx;
    const float4* rh4 = (const float4*)sh_rh;
    const size_t wbase = (size_t)js * NK4 * NCOL;   // in float4/uint2 units

    // one-time staging
    if (tid < TENC) sh_ectx[tid] = ectx_g[b*TENC + tid];
    if (tid >= 256) sh_u[tid - 256] = u[js*128 + (tid - 256)];
    const float bias_c = bias[gate*512 + js*128 + jp];

    for (int t = 0; t < TDEC; ++t) {
        // ----- stage x_t (independent of events) -----
        __syncthreads();
        if (tid < DIN) sh_kx[tid] = inp[((size_t)b*TDEC + t)*DIN + tid];
        __syncthreads();

        // ----- x-part dots: k4 [0,64) for all cols -----
        float acc = dotrange<BF>(wpv, wbase, c, 0, 64, kx4, 0, bias_c);

        // ----- waitC(t-1): h_prev + hdot -----
        if (t > 0) {
            if (tid == 0) {
                wait4(&cnt[((t-1)*3 + 2)*64 + b]);
                float s0 = ldA(&hdotP[(t-1)*256 + b*4 + 0]);
                float s1 = ldA(&hdotP[(t-1)*256 + b*4 + 1]);
                float s2 = ldA(&hdotP[(t-1)*256 + b*4 + 2]);
                float s3 = ldA(&hdotP[(t-1)*256 + b*4 + 3]);
                sh_scal = (s0 + s1) + (s2 + s3);
            }
            __syncthreads();
            for (int i = tid; i < HHH; i += 384) sh_kx[768 + i] = ldA(&hG[b*HHH + i]);
        } else {
            if (tid == 0) sh_scal = 0.f;
            for (int i = tid; i < HHH; i += 384) sh_kx[768 + i] = 0.f;
        }
        __syncthreads();
        const float hd = sh_scal;

        // ----- attention softmax (threads 0..255, waves 0..3) -----
        if (tid < TENC) {
            float e = fmaxf(hd + sh_ectx[tid], 0.f);
            float wm = wave_max(e);
            if ((tid & 63) == 0) sh_red[w] = wm;
            __syncthreads();
            float mx = fmaxf(fmaxf(sh_red[0], sh_red[1]), fmaxf(sh_red[2], sh_red[3]));
            float ex = __expf(e - mx);
            float wse = wave_sum(ex);
            __syncthreads();
            if ((tid & 63) == 0) sh_red[w] = wse;
            __syncthreads();
            float dn = sh_red[0] + sh_red[1] + sh_red[2] + sh_red[3];
            sh_att[tid] = ex / dn;
        } else {
            __syncthreads(); __syncthreads(); __syncthreads();
        }
        __syncthreads();

        // ----- ctx slice: ctx[js*128+dp] = sum_q att[q]*C[b,q,js*128+dp] -----
        if (tid < TENC) {
            const int dp = tid & 127, hf = tid >> 7;
            const float* Cb = C + ((size_t)b*TENC + hf*128)*DENC + js*128 + dp;
            float a = 0.f;
#pragma unroll 8
            for (int q = 0; q < 128; ++q) a = fmaf(sh_att[hf*128 + q], Cb[(size_t)q*DENC], a);
            sh_cred[hf][dp] = a;
        }
        __syncthreads();
        if (tid < 128) stA(&ctxG[b*HHH + js*128 + tid], sh_cred[0][tid] + sh_cred[1][tid]);
        __syncthreads();
        if (tid == 0) arrive(&cnt[(t*3 + 0)*64 + b]);       // event A: ctx slice ready

        // ----- h-part dots: k4 [192,320) for z,r cols -----
        if (t > 0 && c < 256)
            acc = dotrange<BF>(wpv, wbase, c, 192, 320, kx4, 0, acc);

        // ----- waitA: stage full ctx, ctx-part dots k4 [64,192) -----
        if (tid == 0) wait4(&cnt[(t*3 + 0)*64 + b]);
        __syncthreads();
        for (int i = tid; i < HHH; i += 384) sh_kx[256 + i] = ldA(&ctxG[b*HHH + i]);
        __syncthreads();
        acc = dotrange<BF>(wpv, wbase, c, 64, 192, kx4, 0, acc);

        // ----- z, r finish; publish rh -----
        if (gate == 0) {
            sh_z[jp] = 1.f / (1.f + __expf(-acc));
        } else if (gate == 1) {
            float r = 1.f / (1.f + __expf(-acc));
            stA(&rhG[b*HHH + js*128 + jp], r * sh_kx[768 + js*128 + jp]);
        }
        __syncthreads();
        if (tid == 0) arrive(&cnt[(t*3 + 1)*64 + b]);       // event B: rh slice ready

        // ----- waitB: stage rh, rh-part dots k4 [192,320) for gate-h cols -----
        if (tid == 0) wait4(&cnt[(t*3 + 1)*64 + b]);
        __syncthreads();
        for (int i = tid; i < HHH; i += 384) sh_rh[i] = ldA(&rhG[b*HHH + i]);
        __syncthreads();

        if (gate == 2) {
            acc = dotrange<BF>(wpv, wbase, c, 192, 320, rh4, 192, acc);
            // finish: h_new
            float hh = tanhf(acc);
            float z  = sh_z[jp];
            float hp = sh_kx[768 + js*128 + jp];
            float hn = z*hp + (1.f - z)*hh;
            stA(&hG[b*HHH + js*128 + jp], hn);
            out[((size_t)b*TDEC + t)*HHH + js*128 + jp] = hn;
            float p = sh_u[jp] * hn;
            float s = wave_sum(p);
            if ((tid & 63) == 0) sh_red[w] = s;             // waves 4,5
        }
        __syncthreads();
        if (tid == 0) {
            stA(&hdotP[t*256 + b*4 + js], sh_red[4] + sh_red[5]);
            arrive(&cnt[(t*3 + 2)*64 + b]);                 // event C: h + hdot ready
        }
    }
}

extern "C" void kernel_launch(void* const* d_in, const int* in_sizes, int n_in,
                              void* d_out, int out_size, void* d_ws, size_t ws_size,
                              hipStream_t stream) {
    const float* inputs = (const float*)d_in[0];
    const float* C      = (const float*)d_in[1];
    const float* w1     = (const float*)d_in[2];
    const float* w2     = (const float*)d_in[3];
    const float* Wx     = (const float*)d_in[4];
    const float* Wh     = (const float*)d_in[5];
    const float* bias   = (const float*)d_in[6];
    float* out = (float*)d_out;
    float* ws  = (float*)d_ws;

    hipMemsetAsync(ws, 0, 128*3*64*sizeof(unsigned), stream);

    k_u   <<<1024, 64,  0, stream>>>(w1, w2, ws + OFF_U);
    k_ectx<<<(BB*TENC)/4, 256, 0, stream>>>(C, ws + OFF_U, ws + OFF_ECTX);

    const size_t need_f32 = (size_t)(OFF_WP) * 4u + (size_t)WP_ELEMS * 4u;
    void* wp = (void*)(ws + OFF_WP);
    if (ws_size >= need_f32) {
        k_wpack<false><<<WP_ELEMS/256, 256, 0, stream>>>(Wx, Wh, wp);
        decoder<false><<<256, 384, 0, stream>>>(inputs, C, bias, wp,
                                                ws + OFF_U, ws + OFF_ECTX, out, ws);
    } else {
        k_wpack<true><<<WP_ELEMS/256, 256, 0, stream>>>(Wx, Wh, wp);
        decoder<true><<<256, 384, 0, stream>>>(inputs, C, bias, wp,
                                               ws + OFF_U, ws + OFF_ECTX, out, ws);
    }
}